// Round 11
// baseline (214.863 us; speedup 1.0000x reference)
//
#include <hip/hip_runtime.h>
#include <hip/hip_bf16.h>
#include <math.h>

#define B_ 4
#define N_ 2048
#define D_ 512
#define H_ 8
// NORM * log2(e): scores pre-scaled so softmax uses exp2 directly.
#define NORM2_ 0.18033688011112042f

typedef __attribute__((ext_vector_type(8))) short short8;   // 8 bf16 (4 VGPRs)
typedef __attribute__((ext_vector_type(4))) float f32x4;    // MFMA C/D
#define MFMA16(a, b, c) __builtin_amdgcn_mfma_f32_16x16x32_bf16(a, b, c, 0, 0, 0)
#define EXP2(x) __builtin_amdgcn_exp2f(x)

// pack two f32 -> two bf16 (RNE, native v_cvt_pk_bf16_f32); .x at low half
static __device__ __forceinline__ uint32_t pk2(float lo, float hi) {
  __hip_bfloat162 h = __float22bfloat162_rn(make_float2(lo, hi));
  return *(reinterpret_cast<uint32_t*>(&h));
}

// async global->LDS, 16B per lane. LDS dest must be wave-uniform base + lane*16.
static __device__ __forceinline__ void async16(const ushort* lds, const ushort* g) {
  __builtin_amdgcn_global_load_lds(
      (const __attribute__((address_space(1))) uint32_t*)g,
      (__attribute__((address_space(3))) uint32_t*)(ushort*)lds, 16, 0, 0);
}

// ---------------- fused prep: mask pack + all fp32->bf16 conversions (r1-verified) -----------
__global__ __launch_bounds__(256) void prep(const float* __restrict__ q,
                                            const int* __restrict__ mask,
                                            const float* __restrict__ wq,
                                            const float* __restrict__ wk,
                                            const float* __restrict__ wc,
                                            ushort* __restrict__ Xb,
                                            ushort* __restrict__ Wb,
                                            uint32_t* __restrict__ pk) {
  const int bx = blockIdx.x;
  if (bx < 2048) {
    const int lane = threadIdx.x & 63;
    const int wid = ((bx << 8) + threadIdx.x) >> 6;  // 8192 waves
    for (int i = wid; i < 65536; i += 8192) {        // 256-key chunks
      const int4 m = ((const int4*)mask)[(size_t)i * 64 + lane];
      uint32_t nib = (uint32_t)(m.x != 0) | ((uint32_t)(m.y != 0) << 1) |
                     ((uint32_t)(m.z != 0) << 2) | ((uint32_t)(m.w != 0) << 3);
      nib |= __shfl_xor(nib, 1) << 4;
      nib |= __shfl_xor(nib, 2) << 8;
      nib |= __shfl_xor(nib, 4) << 16;
      if ((lane & 7) == 0) pk[i * 8 + (lane >> 3)] = nib;
    }
  } else if (bx < 3072) {
    const int i = ((bx - 2048) << 8) + threadIdx.x;
    for (int j = i; j < 1048576; j += 262144) {
      const float4 v = ((const float4*)q)[j];
      uint2 o; o.x = pk2(v.x, v.y); o.y = pk2(v.z, v.w);
      ((uint2*)Xb)[j] = o;
    }
  } else {
    const int i = ((bx - 3072) << 8) + threadIdx.x;
    for (int j = i; j < 196608; j += 24576) {
      const int wi = j >> 16, off = j & 65535;
      const float* src = (wi == 0) ? wq : (wi == 1) ? wk : wc;
      const float4 v = ((const float4*)src)[off];
      uint2 o; o.x = pk2(v.x, v.y); o.y = pk2(v.z, v.w);
      ((uint2*)Wb)[j] = o;
    }
  }
}

// ---------------- merge: Ab = bf16((P0 + P1) / suml), in-place over P1 ----------------
// l buffers now hold TWO partials each (per wk key-half): l[0][...] and l[1][...].
__global__ __launch_bounds__(256) void merge(const ushort* __restrict__ P0,
                                             const float* __restrict__ l0,
                                             const float* __restrict__ l1,
                                             ushort* __restrict__ Ab) {
  const int j = (blockIdx.x << 8) + threadIdx.x;  // 0..524287, 8 bf16 each
  const int h = (j >> 3) & 7;
  const int tok = j >> 6;                          // b*N + n
  const int b = tok >> 11, n = tok & 2047;
  const int li = ((b * H_ + h) << 11) + n;
  const float inv =
      1.f / (l0[li] + l0[65536 + li] + l1[li] + l1[65536 + li]);
  const uint4 a0 = ((const uint4*)P0)[j];
  const uint4 a1 = ((const uint4*)Ab)[j];  // P1 aliases Ab
  uint4 o;
  const uint32_t* u0 = (const uint32_t*)&a0;
  const uint32_t* u1 = (const uint32_t*)&a1;
  uint32_t* uo = (uint32_t*)&o;
#pragma unroll
  for (int m = 0; m < 4; ++m) {
    const float lo = __uint_as_float(u0[m] << 16) + __uint_as_float(u1[m] << 16);
    const float hi = __uint_as_float(u0[m] & 0xFFFF0000u) +
                     __uint_as_float(u1[m] & 0xFFFF0000u);
    uo[m] = pk2(lo * inv, hi * inv);
  }
  ((uint4*)Ab)[j] = o;
}

// ---------------- 128x128 bf16 MFMA GEMM: C = X @ W^T (r9-verified 2-phase) ----------------
template <int F32OUT>
__global__ __launch_bounds__(256) void gemm128(const ushort* __restrict__ X,
                                               const ushort* __restrict__ W0,
                                               const ushort* __restrict__ W1,
                                               void* __restrict__ C0,
                                               void* __restrict__ C1,
                                               float s0, float s1) {
  const ushort* Wp = (blockIdx.z == 0) ? W0 : W1;
  void* Cp = (blockIdx.z == 0) ? C0 : C1;
  const float sc = (blockIdx.z == 0) ? s0 : s1;
  const int t = threadIdx.x;
  const int w = t >> 6, lane = t & 63, quad = lane >> 4, c = lane & 15;
  const int wm = w & 1, wn = w >> 1;
  const int n0 = blockIdx.x * 128, m0 = blockIdx.y * 128;
  __shared__ __align__(16) ushort Xs[2][128][64];
  __shared__ __align__(16) ushort Ws[2][128][64];
  f32x4 acc[4][4];
#pragma unroll
  for (int i = 0; i < 4; ++i)
#pragma unroll
    for (int j = 0; j < 4; ++j) acc[i][j] = (f32x4){0.f, 0.f, 0.f, 0.f};

#define GSTAGE(bf, k0)                                                        \
  do {                                                                        \
    _Pragma("unroll") for (int g = 0; g < 4; ++g) {                           \
      const int id = w * 256 + g * 64 + lane;                                 \
      const int row = id >> 3, lch = id & 7;                                  \
      const int gch = lch ^ (row & 7);                                        \
      async16(&Xs[bf][row][lch * 8], X + (size_t)(m0 + row) * D_ + (k0) + gch * 8); \
      async16(&Ws[bf][row][lch * 8], Wp + (size_t)(n0 + row) * D_ + (k0) + gch * 8); \
    }                                                                         \
  } while (0)

  GSTAGE(0, 0);
  __syncthreads();  // buf0 landed (implicit vmcnt drain)
  const int NK = D_ / 64;  // 8
  for (int kt = 0; kt < NK; ++kt) {
    const int bf = kt & 1;
    if (kt + 1 < NK) GSTAGE(bf ^ 1, (kt + 1) * 64);  // prefetch next (hidden under MFMA)
#pragma unroll
    for (int s = 0; s < 2; ++s) {
      short8 af[4], bt[4];
#pragma unroll
      for (int i = 0; i < 4; ++i) {
        const int rA = wn * 64 + i * 16 + c;
        af[i] = *(const short8*)&Ws[bf][rA][(((s * 4 + quad) ^ (rA & 7)) & 7) * 8];
        const int rB = wm * 64 + i * 16 + c;
        bt[i] = *(const short8*)&Xs[bf][rB][(((s * 4 + quad) ^ (rB & 7)) & 7) * 8];
      }
#pragma unroll
      for (int i = 0; i < 4; ++i)
#pragma unroll
        for (int j = 0; j < 4; ++j) acc[i][j] = MFMA16(af[i], bt[j], acc[i][j]);
    }
    if (kt + 1 < NK) __syncthreads();  // drain prefetch + protect buf reuse
  }
#undef GSTAGE
#pragma unroll
  for (int i = 0; i < 4; ++i)
#pragma unroll
    for (int j = 0; j < 4; ++j) {
      const size_t off =
          (size_t)(m0 + wm * 64 + j * 16 + c) * D_ + n0 + wn * 64 + i * 16 + quad * 4;
      if (F32OUT) {
        float4 v; v.x = acc[i][j][0]; v.y = acc[i][j][1]; v.z = acc[i][j][2]; v.w = acc[i][j][3];
        *(float4*)((float*)Cp + off) = v;
      } else {
        uint2 uv;
        uv.x = pk2(acc[i][j][0] * sc, acc[i][j][1] * sc);
        uv.y = pk2(acc[i][j][2] * sc, acc[i][j][3] * sc);
        *(uint2*)((ushort*)Cp + off) = uv;
      }
    }
}

// ---------------- flash attention: 2x2 wave split, halved per-wave LDS reads ----------------
// Wave (wq=w&1, wk=w>>1) owns q rows [wq*32,+32) x tile keys [wk*32,+32).
// aK: 4 b128 reads/tile (was 8); aV: 4 (was 8); MFMA/exp2 counts unchanged.
// P in PqN[w][32q][40] (own-wave roundtrip, 16B-aligned reads at [q][quad*8]).
// Cross-wave O: wk=0 publishes partial to LDS once after loop; wk=1 adds+stores.
// Partial l stored per (hf, wk): merge sums 4 terms.  Staging = r8-verified.
__global__ __launch_bounds__(256) void attn_mfma(const ushort* __restrict__ Qb,
                                                 const ushort* __restrict__ Kb,
                                                 const uint32_t* __restrict__ pk,
                                                 ushort* __restrict__ P0,
                                                 ushort* __restrict__ P1,
                                                 float* __restrict__ l0,
                                                 float* __restrict__ l1) {
  const int qt64 = blockIdx.x >> 1, hf = blockIdx.x & 1;
  const int h = blockIdx.y, b = blockIdx.z;
  const int q0 = qt64 * 64;
  const int t = threadIdx.x;
  const int w = t >> 6, lane = t & 63, quad = lane >> 4, c = lane & 15;
  const int wq = w & 1, wk = w >> 1;

  __shared__ __align__(16) ushort Ks[64][64];        // 8K: K rows, swizzled chunks
  __shared__ __align__(16) uint32_t KtU[64][32];     // 8K: V^T key-pair u32, swizzled
  __shared__ __align__(16) unsigned char U[16896];   // Qs(8K) -> PqN(10.2K) -> Ored(16.9K)
  ushort(*Qs)[64] = (ushort(*)[64])U;
  ushort(*PqN)[32][40] = (ushort(*)[32][40])U;       // [wave][q-local][k + pad]
  float* Ored = (float*)U;                           // [2 wq][64 d][33]

  // ---- stage Q once (async DMA) ----
#pragma unroll
  for (int p = 0; p < 2; ++p) {
    const int id = t + p * 256;
    const int row = id >> 3, lch = id & 7, gch = lch ^ (row & 7);
    async16(&Qs[row][lch * 8], Qb + (size_t)(b * N_ + q0 + row) * D_ + h * 64 + gch * 8);
  }
  __syncthreads();
  // ---- Q fragments: 2 q-subtiles per wave ----
  short8 bq0[2], bq1[2];
#pragma unroll
  for (int sq = 0; sq < 2; ++sq) {
    const int rq = wq * 32 + sq * 16 + c;
    bq0[sq] = *(const short8*)&Qs[rq][((quad ^ (rq & 7)) & 7) * 8];
    bq1[sq] = *(const short8*)&Qs[rq][(((4 + quad) ^ (rq & 7)) & 7) * 8];
  }

  short8 vones;
#pragma unroll
  for (int i = 0; i < 8; ++i) vones[i] = (short)0x3F80;  // bf16 1.0 splat

  f32x4 o[4][2];  // [d-tile][q-subtile], contraction over wave's 32 keys
#pragma unroll
  for (int i = 0; i < 4; ++i)
#pragma unroll
    for (int sq = 0; sq < 2; ++sq) o[i][sq] = (f32x4){0.f, 0.f, 0.f, 0.f};
  f32x4 o5[2];
  o5[0] = (f32x4){0.f, 0.f, 0.f, 0.f};
  o5[1] = (f32x4){0.f, 0.f, 0.f, 0.f};

  // staging roles (r8-verified): key-pair, d-chunk
  const int kp = t >> 3, ch = t & 7;
  const int r0 = 2 * kp, r1 = r0 + 1;
  const int ksw0 = ((ch ^ (r0 & 7)) & 7) * 8, ksw1 = ((ch ^ (r1 & 7)) & 7) * 8;
  const ushort* kb0 =
      Kb + (size_t)(b * N_ + hf * 1024 + 2 * kp) * D_ + h * 64 + ch * 8;
  // mask words: word = hf*32 + wk + 2*kt within the q-row's 64 words
  const uint32_t* pkq0 =
      pk + ((size_t)(b * N_ + q0 + wq * 32 + c) << 6) + hf * 32 + wk;
  const uint32_t* pkq1 = pkq0 + (16 << 6);  // q +16

  // prefetched tile data (registers)
  uint4 c0 = *(const uint4*)kb0;
  uint4 c1 = *(const uint4*)(kb0 + D_);
  uint32_t cm0 = pkq0[0], cm1 = pkq1[0];
  uint4 nx0, nx1; uint32_t nxm0, nxm1;

  const int NT = 16;  // half the keys (key-split x2 grid)
  for (int kt = 0; kt < NT; ++kt) {
    __syncthreads();  // prior tile's frag reads (and initial Qs reads) done
    // ---- stage K tile from registers (rows + u32 key-pair transpose) ----
    *(uint4*)&Ks[r0][ksw0] = c0;
    *(uint4*)&Ks[r1][ksw1] = c1;
    const uint32_t* a0 = (const uint32_t*)&c0;
    const uint32_t* a1 = (const uint32_t*)&c1;
#pragma unroll
    for (int m = 0; m < 4; ++m) {
      const uint32_t lo = __builtin_amdgcn_perm(a1[m], a0[m], 0x05040100);  // even d
      const uint32_t hi = __builtin_amdgcn_perm(a1[m], a0[m], 0x07060302);  // odd d
      const int j0 = 2 * m, j1 = 2 * m + 1;
      KtU[ch * 8 + j0][(kp & 3) | ((((kp >> 2) ^ j0 ^ ch) & 7) << 2)] = lo;
      KtU[ch * 8 + j1][(kp & 3) | ((((kp >> 2) ^ j1 ^ ch) & 7) << 2)] = hi;
    }
    __syncthreads();

    if (kt + 1 < NT) {  // prefetch next tile while computing
      const ushort* kbn = kb0 + (size_t)(kt + 1) * 64 * D_;
      nx0 = *(const uint4*)kbn;
      nx1 = *(const uint4*)(kbn + D_);
      nxm0 = pkq0[(kt + 1) * 2];
      nxm1 = pkq1[(kt + 1) * 2];
    }

    // ---- S^T = K.Q^T over wave's 32 keys x 32 q ----
#pragma unroll
    for (int tK = 0; tK < 2; ++tK) {
      const int rk = wk * 32 + tK * 16 + c;
      const short8 aK0 = *(const short8*)&Ks[rk][((quad ^ (rk & 7)) & 7) * 8];
      const short8 aK1 = *(const short8*)&Ks[rk][(((4 + quad) ^ (rk & 7)) & 7) * 8];
#pragma unroll
      for (int sq = 0; sq < 2; ++sq) {
        f32x4 z = (f32x4){0.f, 0.f, 0.f, 0.f};
        z = MFMA16(aK0, bq0[sq], z);
        z = MFMA16(aK1, bq1[sq], z);
        const uint32_t mw = sq ? cm1 : cm0;
        const int bb = tK * 16 + quad * 4;
        uint32_t pb[4];
#pragma unroll
        for (int r = 0; r < 4; ++r) {
          const float e = EXP2(z[r]);                       // unconditional
          pb[r] = ((mw >> (bb + r)) & 1u) ? 0u : __float_as_uint(e);
        }
        const uint32_t pw0 = __builtin_amdgcn_perm(pb[1], pb[0], 0x07060302);
        const uint32_t pw1 = __builtin_amdgcn_perm(pb[3], pb[2], 0x07060302);
        *(uint2*)&PqN[w][sq * 16 + c][tK * 16 + quad * 4] = make_uint2(pw0, pw1);
      }
    }

    // ---- O^T(partial) += V^T . P^T over wave's 32 keys; l via ones-MFMA ----
    const short8 bp0 = *(const short8*)&PqN[w][c][quad * 8];        // sq=0
    const short8 bp1 = *(const short8*)&PqN[w][16 + c][quad * 8];   // sq=1
    o5[0] = MFMA16(vones, bp0, o5[0]);
    o5[1] = MFMA16(vones, bp1, o5[1]);
#pragma unroll
    for (int dt = 0; dt < 4; ++dt) {
      const int dd = dt * 16 + c;
      const int g2 = (((wk << 2) + quad) ^ (c & 7) ^ ((2 * dt + (c >> 3)) & 7)) & 7;
      const short8 aV = *(const short8*)&KtU[dd][g2 << 2];
      o[dt][0] = MFMA16(aV, bp0, o[dt][0]);
      o[dt][1] = MFMA16(aV, bp1, o[dt][1]);
    }

    if (kt + 1 < NT) { c0 = nx0; c1 = nx1; cm0 = nxm0; cm1 = nxm1; }
  }

  // ---- partial l store (per hf, per wk region; merge sums 4 terms) ----
  float* lp = hf ? l1 : l0;
  if (quad == 0) {
#pragma unroll
    for (int sq = 0; sq < 2; ++sq)
      lp[wk * 65536 + ((b * H_ + h) << 11) + q0 + wq * 32 + sq * 16 + c] = o5[sq][0];
  }

  // ---- cross-wave O reduction: wk=0 publishes, wk=1 adds + stores bf16 ----
  __syncthreads();  // all PV reads of PqN/Ks/KtU done; U reusable as Ored
  if (wk == 0) {
#pragma unroll
    for (int dt = 0; dt < 4; ++dt)
#pragma unroll
      for (int sq = 0; sq < 2; ++sq)
#pragma unroll
        for (int jj = 0; jj < 4; ++jj)
          Ored[wq * 2112 + (dt * 16 + quad * 4 + jj) * 33 + sq * 16 + c] =
              o[dt][sq][jj];
  }
  __syncthreads();
  if (wk == 1) {
    ushort* Pp = hf ? P1 : P0;
#pragma unroll
    for (int dt = 0; dt < 4; ++dt)
#pragma unroll
      for (int sq = 0; sq < 2; ++sq) {
        float r[4];
#pragma unroll
        for (int jj = 0; jj < 4; ++jj)
          r[jj] = o[dt][sq][jj] +
                  Ored[wq * 2112 + (dt * 16 + quad * 4 + jj) * 33 + sq * 16 + c];
        uint2 uv;
        uv.x = pk2(r[0], r[1]);
        uv.y = pk2(r[2], r[3]);
        *(uint2*)(Pp + (size_t)(b * N_ + q0 + wq * 32 + sq * 16 + c) * D_ + h * 64 +
                  dt * 16 + quad * 4) = uv;
      }
  }
}

extern "C" void kernel_launch(void* const* d_in, const int* in_sizes, int n_in,
                              void* d_out, int out_size, void* d_ws, size_t ws_size,
                              hipStream_t stream) {
  const float* queries = (const float*)d_in[0];
  const int* mask = (const int*)d_in[1];
  const float* Wq = (const float*)d_in[2];
  const float* Wk = (const float*)d_in[3];
  const float* Wc = (const float*)d_in[4];
  float* out = (float*)d_out;

  const size_t nTok = (size_t)B_ * N_;
  const size_t nXD = nTok * D_;
  const size_t nW = (size_t)D_ * D_;
  ushort* Xb = (ushort*)d_ws;
  ushort* Wqb = Xb + nXD;     // Wq|Wk|Wc contiguous
  ushort* Wkb = Wqb + nW;
  ushort* Wcb = Wkb + nW;
  ushort* Qb = Wcb + nW;
  ushort* Kb = Qb + nXD;
  ushort* Ab = Kb + nXD;
  uint32_t* pk = (uint32_t*)(Ab + nXD);
  // dead-region reuse during attn (all within verified footprint):
  ushort* P0 = Xb;            // bf16 partial O, half 0 (Xb dead after gemm<0>)
  ushort* P1 = Ab;            // bf16 partial O, half 1 (merged in-place into Ab)
  float* l0 = (float*)Wqb;    // [2 wk][65536] f32 = 512 KB = dead Wqb exactly
  float* l1 = (float*)Wkb;    // [2 wk][65536] f32 = dead Wkb

  prep<<<3168, 256, 0, stream>>>(queries, mask, Wq, Wk, Wc, Xb, Wqb, pk);
  gemm128<0><<<dim3(D_ / 128, (int)(nTok / 128), 2), 256, 0, stream>>>(
      Xb, Wqb, Wkb, Qb, Kb, NORM2_, 1.0f);
  attn_mfma<<<dim3(64, H_, B_), 256, 0, stream>>>(Qb, Kb, pk, P0, P1, l0, l1);
  merge<<<2048, 256, 0, stream>>>(P0, l0, l1, Ab);
  gemm128<1><<<dim3(D_ / 128, (int)(nTok / 128), 1), 256, 0, stream>>>(
      Ab, Wcb, nullptr, out, nullptr, 1.0f, 1.0f);
}

// Round 12
// 212.003 us; speedup vs baseline: 1.0135x; 1.0135x over previous
//
#include <hip/hip_runtime.h>
#include <hip/hip_bf16.h>
#include <math.h>

#define B_ 4
#define N_ 2048
#define D_ 512
#define H_ 8
// NORM * log2(e): scores pre-scaled so softmax uses exp2 directly.
#define NORM2_ 0.18033688011112042f

typedef __attribute__((ext_vector_type(8))) short short8;   // 8 bf16 (4 VGPRs)
typedef __attribute__((ext_vector_type(4))) float f32x4;    // MFMA C/D
#define MFMA16(a, b, c) __builtin_amdgcn_mfma_f32_16x16x32_bf16(a, b, c, 0, 0, 0)
#define EXP2(x) __builtin_amdgcn_exp2f(x)

// pack two f32 -> two bf16 (RNE, native v_cvt_pk_bf16_f32); .x at low half
static __device__ __forceinline__ uint32_t pk2(float lo, float hi) {
  __hip_bfloat162 h = __float22bfloat162_rn(make_float2(lo, hi));
  return *(reinterpret_cast<uint32_t*>(&h));
}

// async global->LDS, 16B per lane. LDS dest must be wave-uniform base + lane*16.
static __device__ __forceinline__ void async16(const ushort* lds, const ushort* g) {
  __builtin_amdgcn_global_load_lds(
      (const __attribute__((address_space(1))) uint32_t*)g,
      (__attribute__((address_space(3))) uint32_t*)(ushort*)lds, 16, 0, 0);
}

// ---------------- fused prep: mask pack + all fp32->bf16 conversions (r1-verified) -----------
__global__ __launch_bounds__(256) void prep(const float* __restrict__ q,
                                            const int* __restrict__ mask,
                                            const float* __restrict__ wq,
                                            const float* __restrict__ wk,
                                            const float* __restrict__ wc,
                                            ushort* __restrict__ Xb,
                                            ushort* __restrict__ Wb,
                                            uint32_t* __restrict__ pk) {
  const int bx = blockIdx.x;
  if (bx < 2048) {
    const int lane = threadIdx.x & 63;
    const int wid = ((bx << 8) + threadIdx.x) >> 6;  // 8192 waves
    for (int i = wid; i < 65536; i += 8192) {        // 256-key chunks
      const int4 m = ((const int4*)mask)[(size_t)i * 64 + lane];
      uint32_t nib = (uint32_t)(m.x != 0) | ((uint32_t)(m.y != 0) << 1) |
                     ((uint32_t)(m.z != 0) << 2) | ((uint32_t)(m.w != 0) << 3);
      nib |= __shfl_xor(nib, 1) << 4;
      nib |= __shfl_xor(nib, 2) << 8;
      nib |= __shfl_xor(nib, 4) << 16;
      if ((lane & 7) == 0) pk[i * 8 + (lane >> 3)] = nib;
    }
  } else if (bx < 3072) {
    const int i = ((bx - 2048) << 8) + threadIdx.x;
    for (int j = i; j < 1048576; j += 262144) {
      const float4 v = ((const float4*)q)[j];
      uint2 o; o.x = pk2(v.x, v.y); o.y = pk2(v.z, v.w);
      ((uint2*)Xb)[j] = o;
    }
  } else {
    const int i = ((bx - 3072) << 8) + threadIdx.x;
    for (int j = i; j < 196608; j += 24576) {
      const int wi = j >> 16, off = j & 65535;
      const float* src = (wi == 0) ? wq : (wi == 1) ? wk : wc;
      const float4 v = ((const float4*)src)[off];
      uint2 o; o.x = pk2(v.x, v.y); o.y = pk2(v.z, v.w);
      ((uint2*)Wb)[j] = o;
    }
  }
}

// ---------------- Q/K projection GEMM: 128x128 tile, 8 waves (wave = 64x32) ----------------
__global__ __launch_bounds__(512) void gemmQK(const ushort* __restrict__ X,
                                              const ushort* __restrict__ W0,
                                              const ushort* __restrict__ W1,
                                              ushort* __restrict__ C0,
                                              ushort* __restrict__ C1,
                                              float s0, float s1) {
  const ushort* Wp = blockIdx.z ? W1 : W0;
  ushort* Cp = blockIdx.z ? C1 : C0;
  const float sc = blockIdx.z ? s1 : s0;
  const int t = threadIdx.x;
  const int w = t >> 6, lane = t & 63, quad = lane >> 4, c = lane & 15;
  const int wm = w & 1, wn = w >> 1;  // M-half, N-quarter
  const int n0 = blockIdx.x * 128, m0 = blockIdx.y * 128;
  __shared__ __align__(16) ushort Xs[2][128][64];
  __shared__ __align__(16) ushort Ws[2][128][64];
  f32x4 acc[2][4];
#pragma unroll
  for (int i = 0; i < 2; ++i)
#pragma unroll
    for (int j = 0; j < 4; ++j) acc[i][j] = (f32x4){0.f, 0.f, 0.f, 0.f};

#define GSTAGE(bf, k0)                                                              \
  do {                                                                              \
    _Pragma("unroll") for (int p = 0; p < 2; ++p) {                                 \
      const int id = t + p * 512;                                                   \
      const int row = id >> 3, lch = id & 7;                                        \
      const int gch = lch ^ (row & 7);                                              \
      async16(&Xs[bf][row][lch * 8], X + (size_t)(m0 + row) * D_ + (k0) + gch * 8); \
      async16(&Ws[bf][row][lch * 8], Wp + (size_t)(n0 + row) * D_ + (k0) + gch * 8); \
    }                                                                               \
  } while (0)

  GSTAGE(0, 0);
  __syncthreads();
  const int NK = D_ / 64;  // 8
  for (int kt = 0; kt < NK; ++kt) {
    const int bf = kt & 1;
    if (kt + 1 < NK) GSTAGE(bf ^ 1, (kt + 1) * 64);  // prefetch hidden under MFMA
#pragma unroll
    for (int s = 0; s < 2; ++s) {
      short8 af[2], bt[4];
#pragma unroll
      for (int i = 0; i < 2; ++i) {
        const int rA = wn * 32 + i * 16 + c;
        af[i] = *(const short8*)&Ws[bf][rA][(((s * 4 + quad) ^ (rA & 7)) & 7) * 8];
      }
#pragma unroll
      for (int j = 0; j < 4; ++j) {
        const int rB = wm * 64 + j * 16 + c;
        bt[j] = *(const short8*)&Xs[bf][rB][(((s * 4 + quad) ^ (rB & 7)) & 7) * 8];
      }
#pragma unroll
      for (int i = 0; i < 2; ++i)
#pragma unroll
        for (int j = 0; j < 4; ++j) acc[i][j] = MFMA16(af[i], bt[j], acc[i][j]);
    }
    if (kt + 1 < NK) __syncthreads();
  }
#undef GSTAGE
#pragma unroll
  for (int i = 0; i < 2; ++i)
#pragma unroll
    for (int j = 0; j < 4; ++j) {
      const size_t off =
          (size_t)(m0 + wm * 64 + j * 16 + c) * D_ + n0 + wn * 32 + i * 16 + quad * 4;
      uint2 uv;
      uv.x = pk2(acc[i][j][0] * sc, acc[i][j][1] * sc);
      uv.y = pk2(acc[i][j][2] * sc, acc[i][j][3] * sc);
      *(uint2*)(Cp + off) = uv;
    }
}

// ---------------- output GEMM with fused merge: out = ((P0+P1)/l) @ Wc^T ----------------
// X-tile reg-staged from the two bf16 partials + l-divide (r8-verified combine),
// T14 split: loads issued before compute, combined+written after (compiler
// inserts the vmcnt wait at first use). W-tile via async16. 8 waves.
__global__ __launch_bounds__(512) void gemmOut(const ushort* __restrict__ P0,
                                               const ushort* __restrict__ P1,
                                               const float* __restrict__ l0,
                                               const float* __restrict__ l1,
                                               const ushort* __restrict__ W,
                                               float* __restrict__ out) {
  const int t = threadIdx.x;
  const int w = t >> 6, lane = t & 63, quad = lane >> 4, c = lane & 15;
  const int wm = w & 1, wn = w >> 1;
  const int n0 = blockIdx.x * 128, m0 = blockIdx.y * 128;
  __shared__ __align__(16) ushort Xs[2][128][64];
  __shared__ __align__(16) ushort Ws[2][128][64];
  f32x4 acc[2][4];
#pragma unroll
  for (int i = 0; i < 2; ++i)
#pragma unroll
    for (int j = 0; j < 4; ++j) acc[i][j] = (f32x4){0.f, 0.f, 0.f, 0.f};

  uint4 xa[2], xb[2];
  float lsum[2];

#define WSTAGE(bf, k0)                                                              \
  do {                                                                              \
    _Pragma("unroll") for (int p = 0; p < 2; ++p) {                                 \
      const int id = t + p * 512;                                                   \
      const int row = id >> 3, lch = id & 7;                                        \
      const int gch = lch ^ (row & 7);                                              \
      async16(&Ws[bf][row][lch * 8], W + (size_t)(n0 + row) * D_ + (k0) + gch * 8); \
    }                                                                               \
  } while (0)

#define XLOAD(k0)                                                                   \
  do {                                                                              \
    _Pragma("unroll") for (int p = 0; p < 2; ++p) {                                 \
      const int id = t + p * 512;                                                   \
      const int row = id >> 3, lch = id & 7;                                        \
      const int gch = lch ^ (row & 7);                                              \
      const size_t j16 = (size_t)(m0 + row) * D_ + (k0) + gch * 8;                  \
      xa[p] = *(const uint4*)(P0 + j16);                                            \
      xb[p] = *(const uint4*)(P1 + j16);                                            \
      const int tok = m0 + row;                                                     \
      const int li = ((((tok >> 11) * H_) + ((k0) >> 6)) << 11) + (tok & 2047);     \
      lsum[p] = l0[li] + l1[li];                                                    \
    }                                                                               \
  } while (0)

#define XWRITE(bf)                                                                  \
  do {                                                                              \
    _Pragma("unroll") for (int p = 0; p < 2; ++p) {                                 \
      const int id = t + p * 512;                                                   \
      const int row = id >> 3, lch = id & 7;                                        \
      const float inv = 1.f / lsum[p];                                              \
      const uint32_t* u0 = (const uint32_t*)&xa[p];                                 \
      const uint32_t* u1 = (const uint32_t*)&xb[p];                                 \
      uint4 o;                                                                      \
      uint32_t* uo = (uint32_t*)&o;                                                 \
      _Pragma("unroll") for (int m = 0; m < 4; ++m) {                               \
        const float lo = __uint_as_float(u0[m] << 16) + __uint_as_float(u1[m] << 16); \
        const float hi = __uint_as_float(u0[m] & 0xFFFF0000u) +                     \
                         __uint_as_float(u1[m] & 0xFFFF0000u);                      \
        uo[m] = pk2(lo * inv, hi * inv);                                            \
      }                                                                             \
      *(uint4*)&Xs[bf][row][lch * 8] = o;                                           \
    }                                                                               \
  } while (0)

  WSTAGE(0, 0);
  XLOAD(0);
  XWRITE(0);        // compiler waits vmcnt for xa/xb use here
  __syncthreads();  // drains Ws DMA + makes Xs writes visible
  const int NK = D_ / 64;  // 8
  for (int kt = 0; kt < NK; ++kt) {
    const int bf = kt & 1;
    if (kt + 1 < NK) {
      WSTAGE(bf ^ 1, (kt + 1) * 64);
      XLOAD((kt + 1) * 64);  // issue early; consumed after compute (T14)
    }
#pragma unroll
    for (int s = 0; s < 2; ++s) {
      short8 af[2], bt[4];
#pragma unroll
      for (int i = 0; i < 2; ++i) {
        const int rA = wn * 32 + i * 16 + c;
        af[i] = *(const short8*)&Ws[bf][rA][(((s * 4 + quad) ^ (rA & 7)) & 7) * 8];
      }
#pragma unroll
      for (int j = 0; j < 4; ++j) {
        const int rB = wm * 64 + j * 16 + c;
        bt[j] = *(const short8*)&Xs[bf][rB][(((s * 4 + quad) ^ (rB & 7)) & 7) * 8];
      }
#pragma unroll
      for (int i = 0; i < 2; ++i)
#pragma unroll
        for (int j = 0; j < 4; ++j) acc[i][j] = MFMA16(af[i], bt[j], acc[i][j]);
    }
    if (kt + 1 < NK) {
      XWRITE(bf ^ 1);  // loads landed during compute; write other buffer
      __syncthreads();
    }
  }
#undef WSTAGE
#undef XLOAD
#undef XWRITE
#pragma unroll
  for (int i = 0; i < 2; ++i)
#pragma unroll
    for (int j = 0; j < 4; ++j) {
      const size_t off =
          (size_t)(m0 + wm * 64 + j * 16 + c) * D_ + n0 + wn * 32 + i * 16 + quad * 4;
      float4 v;
      v.x = acc[i][j][0]; v.y = acc[i][j][1]; v.z = acc[i][j][2]; v.w = acc[i][j][3];
      *(float4*)(out + off) = v;
    }
}

// ---------------- flash attention: r10-verified 8-wave / 128-q blocks (UNCHANGED) ----------------
__global__ __launch_bounds__(512) void attn_mfma(const ushort* __restrict__ Qb,
                                                 const ushort* __restrict__ Kb,
                                                 const uint32_t* __restrict__ pk,
                                                 ushort* __restrict__ P0,
                                                 ushort* __restrict__ P1,
                                                 float* __restrict__ l0,
                                                 float* __restrict__ l1) {
  const int qt128 = blockIdx.x >> 1, hf = blockIdx.x & 1;
  const int h = blockIdx.y, b = blockIdx.z;
  const int q0 = qt128 * 128;
  const int t = threadIdx.x;
  const int w = t >> 6, lane = t & 63, quad = lane >> 4, c = lane & 15;

  __shared__ __align__(16) ushort Ks[64][64];        // 8K: K rows, swizzled chunks
  __shared__ __align__(16) uint32_t KtU[64][32];     // 8K: V^T key-pair u32, swizzled
  __shared__ __align__(16) ushort QP[8][16][72];     // 18.4K: Qs[128][64] then Pq
  ushort(*Qs)[64] = (ushort(*)[64]) & QP[0][0][0];
  ushort(*Pq)[16][72] = QP;

  // ---- stage Q once (async DMA): 128 rows x 64 = 1024 chunks / 512 threads ----
#pragma unroll
  for (int p = 0; p < 2; ++p) {
    const int id = t + p * 512;
    const int row = id >> 3, lch = id & 7, gch = lch ^ (row & 7);
    async16(&Qs[row][lch * 8], Qb + (size_t)(b * N_ + q0 + row) * D_ + h * 64 + gch * 8);
  }
  __syncthreads();
  const int rq = (w << 4) + c;  // 0..127
  const short8 bq0 = *(const short8*)&Qs[rq][((quad ^ (rq & 7)) & 7) * 8];
  const short8 bq1 = *(const short8*)&Qs[rq][(((4 + quad) ^ (rq & 7)) & 7) * 8];

  short8 vones;
#pragma unroll
  for (int i = 0; i < 8; ++i) vones[i] = (short)0x3F80;  // bf16 1.0 splat

  f32x4 o[4];
#pragma unroll
  for (int i = 0; i < 4; ++i) o[i] = (f32x4){0.f, 0.f, 0.f, 0.f};
  f32x4 o5 = (f32x4){0.f, 0.f, 0.f, 0.f};  // l accumulator (ones-MFMA, rows identical)

  // staging roles (threads 0..255 only): key-pair, d-chunk — r8-verified path
  const int kp = t >> 3, ch = t & 7;
  const int r0 = 2 * kp, r1 = r0 + 1;
  const int ksw0 = ((ch ^ (r0 & 7)) & 7) * 8, ksw1 = ((ch ^ (r1 & 7)) & 7) * 8;
  const ushort* kb0 =
      Kb + (size_t)(b * N_ + hf * 1024 + 2 * kp) * D_ + h * 64 + ch * 8;
  const uint32_t* pkq =
      pk + ((size_t)(b * N_ + q0 + (w << 4) + c) << 6) + hf * 32;

  // prefetched tile data (registers; c0/c1 meaningful for t<256 only)
  uint4 c0, c1;
  if (t < 256) {
    c0 = *(const uint4*)kb0;
    c1 = *(const uint4*)(kb0 + D_);
  }
  uint2 cm = *(const uint2*)pkq;
  uint4 nx0, nx1; uint2 nxm;

  const int NT = 16;  // half the keys
  for (int kt = 0; kt < NT; ++kt) {
    __syncthreads();  // prior tile's frag reads (and initial Qs reads) done
    // ---- stage K tile from registers (rows + u32 key-pair transpose), t<256 ----
    if (t < 256) {
      *(uint4*)&Ks[r0][ksw0] = c0;
      *(uint4*)&Ks[r1][ksw1] = c1;
      const uint32_t* a0 = (const uint32_t*)&c0;
      const uint32_t* a1 = (const uint32_t*)&c1;
#pragma unroll
      for (int m = 0; m < 4; ++m) {
        const uint32_t lo = __builtin_amdgcn_perm(a1[m], a0[m], 0x05040100);  // even d
        const uint32_t hi = __builtin_amdgcn_perm(a1[m], a0[m], 0x07060302);  // odd d
        const int j0 = 2 * m, j1 = 2 * m + 1;
        KtU[ch * 8 + j0][(kp & 3) | ((((kp >> 2) ^ j0 ^ ch) & 7) << 2)] = lo;
        KtU[ch * 8 + j1][(kp & 3) | ((((kp >> 2) ^ j1 ^ ch) & 7) << 2)] = hi;
      }
    }
    __syncthreads();

    if (kt + 1 < NT) {  // prefetch next tile while computing
      if (t < 256) {
        const ushort* kbn = kb0 + (size_t)(kt + 1) * 64 * D_;
        nx0 = *(const uint4*)kbn;
        nx1 = *(const uint4*)(kbn + D_);
      }
      nxm = *(const uint2*)(pkq + (kt + 1) * 2);
    }

    // ---- S^T = K·Q^T; p = masked ? 0 : exp2(s) ----
#pragma unroll
    for (int tI = 0; tI < 4; ++tI) {
      const int rk = tI * 16 + c;
      const short8 aK0 = *(const short8*)&Ks[rk][((quad ^ (rk & 7)) & 7) * 8];
      const short8 aK1 = *(const short8*)&Ks[rk][(((4 + quad) ^ (rk & 7)) & 7) * 8];
      f32x4 z = (f32x4){0.f, 0.f, 0.f, 0.f};
      z = MFMA16(aK0, bq0, z);
      z = MFMA16(aK1, bq1, z);
      const uint32_t mw = (tI < 2) ? cm.x : cm.y;
      const int bb = ((tI & 1) << 4) + quad * 4;
      uint32_t pb[4];
#pragma unroll
      for (int r = 0; r < 4; ++r) {
        const float e = EXP2(z[r]);                       // unconditional
        pb[r] = ((mw >> (bb + r)) & 1u) ? 0u : __float_as_uint(e);
      }
      const uint32_t pw0 = __builtin_amdgcn_perm(pb[1], pb[0], 0x07060302);
      const uint32_t pw1 = __builtin_amdgcn_perm(pb[3], pb[2], 0x07060302);
      *(uint2*)&Pq[w][c][tI * 16 + quad * 4] = make_uint2(pw0, pw1);
    }

    // ---- O^T += V^T·P^T ; l via ones-MFMA ----
    const short8 bp0 = *(const short8*)&Pq[w][c][quad * 8];
    const short8 bp1 = *(const short8*)&Pq[w][c][32 + quad * 8];
    o5 = MFMA16(vones, bp0, o5);
    o5 = MFMA16(vones, bp1, o5);
#pragma unroll
    for (int dt = 0; dt < 4; ++dt) {
      const int dd = dt * 16 + c;
      const int g = (c & 7) ^ ((2 * dt + (c >> 3)) & 7);
      const short8 aV0 = *(const short8*)&KtU[dd][((quad ^ g) & 7) << 2];
      const short8 aV1 = *(const short8*)&KtU[dd][(((4 + quad) ^ g) & 7) << 2];
      o[dt] = MFMA16(aV0, bp0, o[dt]);
      o[dt] = MFMA16(aV1, bp1, o[dt]);
    }

    if (kt + 1 < NT) {
      if (t < 256) { c0 = nx0; c1 = nx1; }
      cm = nxm;
    }
  }

  // ---- epilogue: store PARTIAL O^T (bf16, unscaled) + partial l; no atomics ----
  ushort* Pp = hf ? P1 : P0;
  float* lp = hf ? l1 : l0;
#pragma unroll
  for (int dt = 0; dt < 4; ++dt) {
    uint2 uv;
    uv.x = pk2(o[dt][0], o[dt][1]);
    uv.y = pk2(o[dt][2], o[dt][3]);
    *(uint2*)(Pp + (size_t)(b * N_ + q0 + (w << 4) + c) * D_ + h * 64 + dt * 16 + quad * 4) = uv;
  }
  if (quad == 0) lp[((b * H_ + h) << 11) + q0 + (w << 4) + c] = o5[0];
}

extern "C" void kernel_launch(void* const* d_in, const int* in_sizes, int n_in,
                              void* d_out, int out_size, void* d_ws, size_t ws_size,
                              hipStream_t stream) {
  const float* queries = (const float*)d_in[0];
  const int* mask = (const int*)d_in[1];
  const float* Wq = (const float*)d_in[2];
  const float* Wk = (const float*)d_in[3];
  const float* Wc = (const float*)d_in[4];
  float* out = (float*)d_out;

  const size_t nTok = (size_t)B_ * N_;
  const size_t nXD = nTok * D_;
  const size_t nW = (size_t)D_ * D_;
  ushort* Xb = (ushort*)d_ws;
  ushort* Wqb = Xb + nXD;     // Wq|Wk|Wc contiguous
  ushort* Wkb = Wqb + nW;
  ushort* Wcb = Wkb + nW;
  ushort* Qb = Wcb + nW;
  ushort* Kb = Qb + nXD;
  ushort* Ab = Kb + nXD;
  uint32_t* pk = (uint32_t*)(Ab + nXD);
  // dead-region reuse during attn (all within verified footprint):
  ushort* P0 = Xb;            // bf16 partial O, half 0 (Xb dead after gemmQK)
  ushort* P1 = Ab;            // bf16 partial O, half 1
  float* l0 = (float*)Wqb;    // 256 KB in dead Wqb
  float* l1 = (float*)Wkb;    // 256 KB in dead Wkb

  prep<<<3168, 256, 0, stream>>>(queries, mask, Wq, Wk, Wc, Xb, Wqb, pk);
  gemmQK<<<dim3(D_ / 128, (int)(nTok / 128), 2), 512, 0, stream>>>(
      Xb, Wqb, Wkb, Qb, Kb, NORM2_, 1.0f);
  attn_mfma<<<dim3(32, H_, B_), 512, 0, stream>>>(Qb, Kb, pk, P0, P1, l0, l1);
  gemmOut<<<dim3(D_ / 128, (int)(nTok / 128)), 512, 0, stream>>>(
      P0, P1, l0, l1, Wcb, out);
}

// Round 13
// 209.548 us; speedup vs baseline: 1.0254x; 1.0117x over previous
//
#include <hip/hip_runtime.h>
#include <hip/hip_bf16.h>
#include <math.h>

#define B_ 4
#define N_ 2048
#define D_ 512
#define H_ 8
// NORM * log2(e): scores pre-scaled so softmax uses exp2 directly.
#define NORM2_ 0.18033688011112042f

typedef __attribute__((ext_vector_type(8))) short short8;   // 8 bf16 (4 VGPRs)
typedef __attribute__((ext_vector_type(4))) float f32x4;    // MFMA C/D
#define MFMA16(a, b, c) __builtin_amdgcn_mfma_f32_16x16x32_bf16(a, b, c, 0, 0, 0)
#define EXP2(x) __builtin_amdgcn_exp2f(x)

// pack two f32 -> two bf16 (RNE, native v_cvt_pk_bf16_f32); .x at low half
static __device__ __forceinline__ uint32_t pk2(float lo, float hi) {
  __hip_bfloat162 h = __float22bfloat162_rn(make_float2(lo, hi));
  return *(reinterpret_cast<uint32_t*>(&h));
}

// async global->LDS, 16B per lane. LDS dest must be wave-uniform base + lane*16.
static __device__ __forceinline__ void async16(const ushort* lds, const ushort* g) {
  __builtin_amdgcn_global_load_lds(
      (const __attribute__((address_space(1))) uint32_t*)g,
      (__attribute__((address_space(3))) uint32_t*)(ushort*)lds, 16, 0, 0);
}

// ---------------- fused prep: mask pack + all fp32->bf16 conversions (r1-verified) -----------
__global__ __launch_bounds__(256) void prep(const float* __restrict__ q,
                                            const int* __restrict__ mask,
                                            const float* __restrict__ wq,
                                            const float* __restrict__ wk,
                                            const float* __restrict__ wc,
                                            ushort* __restrict__ Xb,
                                            ushort* __restrict__ Wb,
                                            uint32_t* __restrict__ pk) {
  const int bx = blockIdx.x;
  if (bx < 2048) {
    const int lane = threadIdx.x & 63;
    const int wid = ((bx << 8) + threadIdx.x) >> 6;  // 8192 waves
    for (int i = wid; i < 65536; i += 8192) {        // 256-key chunks
      const int4 m = ((const int4*)mask)[(size_t)i * 64 + lane];
      uint32_t nib = (uint32_t)(m.x != 0) | ((uint32_t)(m.y != 0) << 1) |
                     ((uint32_t)(m.z != 0) << 2) | ((uint32_t)(m.w != 0) << 3);
      nib |= __shfl_xor(nib, 1) << 4;
      nib |= __shfl_xor(nib, 2) << 8;
      nib |= __shfl_xor(nib, 4) << 16;
      if ((lane & 7) == 0) pk[i * 8 + (lane >> 3)] = nib;
    }
  } else if (bx < 3072) {
    const int i = ((bx - 2048) << 8) + threadIdx.x;
    for (int j = i; j < 1048576; j += 262144) {
      const float4 v = ((const float4*)q)[j];
      uint2 o; o.x = pk2(v.x, v.y); o.y = pk2(v.z, v.w);
      ((uint2*)Xb)[j] = o;
    }
  } else {
    const int i = ((bx - 3072) << 8) + threadIdx.x;
    for (int j = i; j < 196608; j += 24576) {
      const int wi = j >> 16, off = j & 65535;
      const float* src = (wi == 0) ? wq : (wi == 1) ? wk : wc;
      const float4 v = ((const float4*)src)[off];
      uint2 o; o.x = pk2(v.x, v.y); o.y = pk2(v.z, v.w);
      ((uint2*)Wb)[j] = o;
    }
  }
}

// ---------------- 128x128 bf16 MFMA GEMM: C = X @ W^T (r9-verified 2-phase, 4 waves) --------
__global__ __launch_bounds__(256) void gemmQK(const ushort* __restrict__ X,
                                              const ushort* __restrict__ W0,
                                              const ushort* __restrict__ W1,
                                              ushort* __restrict__ C0,
                                              ushort* __restrict__ C1,
                                              float s0, float s1) {
  const ushort* Wp = blockIdx.z ? W1 : W0;
  ushort* Cp = blockIdx.z ? C1 : C0;
  const float sc = blockIdx.z ? s1 : s0;
  const int t = threadIdx.x;
  const int w = t >> 6, lane = t & 63, quad = lane >> 4, c = lane & 15;
  const int wm = w & 1, wn = w >> 1;
  const int n0 = blockIdx.x * 128, m0 = blockIdx.y * 128;
  __shared__ __align__(16) ushort Xs[2][128][64];
  __shared__ __align__(16) ushort Ws[2][128][64];
  f32x4 acc[4][4];
#pragma unroll
  for (int i = 0; i < 4; ++i)
#pragma unroll
    for (int j = 0; j < 4; ++j) acc[i][j] = (f32x4){0.f, 0.f, 0.f, 0.f};

#define GSTAGE(bf, k0)                                                        \
  do {                                                                        \
    _Pragma("unroll") for (int g = 0; g < 4; ++g) {                           \
      const int id = w * 256 + g * 64 + lane;                                 \
      const int row = id >> 3, lch = id & 7;                                  \
      const int gch = lch ^ (row & 7);                                        \
      async16(&Xs[bf][row][lch * 8], X + (size_t)(m0 + row) * D_ + (k0) + gch * 8); \
      async16(&Ws[bf][row][lch * 8], Wp + (size_t)(n0 + row) * D_ + (k0) + gch * 8); \
    }                                                                         \
  } while (0)

  GSTAGE(0, 0);
  __syncthreads();  // buf0 landed (implicit vmcnt drain)
  const int NK = D_ / 64;  // 8
  for (int kt = 0; kt < NK; ++kt) {
    const int bf = kt & 1;
    if (kt + 1 < NK) GSTAGE(bf ^ 1, (kt + 1) * 64);  // prefetch next (hidden under MFMA)
#pragma unroll
    for (int s = 0; s < 2; ++s) {
      short8 af[4], bt[4];
#pragma unroll
      for (int i = 0; i < 4; ++i) {
        const int rA = wn * 64 + i * 16 + c;
        af[i] = *(const short8*)&Ws[bf][rA][(((s * 4 + quad) ^ (rA & 7)) & 7) * 8];
        const int rB = wm * 64 + i * 16 + c;
        bt[i] = *(const short8*)&Xs[bf][rB][(((s * 4 + quad) ^ (rB & 7)) & 7) * 8];
      }
#pragma unroll
      for (int i = 0; i < 4; ++i)
#pragma unroll
        for (int j = 0; j < 4; ++j) acc[i][j] = MFMA16(af[i], bt[j], acc[i][j]);
    }
    if (kt + 1 < NK) __syncthreads();  // drain prefetch + protect buf reuse
  }
#undef GSTAGE
#pragma unroll
  for (int i = 0; i < 4; ++i)
#pragma unroll
    for (int j = 0; j < 4; ++j) {
      const size_t off =
          (size_t)(m0 + wm * 64 + j * 16 + c) * D_ + n0 + wn * 64 + i * 16 + quad * 4;
      uint2 uv;
      uv.x = pk2(acc[i][j][0] * sc, acc[i][j][1] * sc);
      uv.y = pk2(acc[i][j][2] * sc, acc[i][j][3] * sc);
      *(uint2*)(Cp + off) = uv;
    }
}

// ---------------- output GEMM with fused merge: out = ((P0+P1)/l) @ Wc^T ----------------
// 4-wave r9 gemm structure; X-tile reg-staged from the two bf16 partials with
// the r12-verified combine (loads issued before MFMA phase, combined+written
// after: T14 split; compiler inserts vmcnt waits at first use).
__global__ __launch_bounds__(256) void gemmOut(const ushort* __restrict__ P0,
                                               const ushort* __restrict__ P1,
                                               const float* __restrict__ l0,
                                               const float* __restrict__ l1,
                                               const ushort* __restrict__ W,
                                               float* __restrict__ out) {
  const int t = threadIdx.x;
  const int w = t >> 6, lane = t & 63, quad = lane >> 4, c = lane & 15;
  const int wm = w & 1, wn = w >> 1;
  const int n0 = blockIdx.x * 128, m0 = blockIdx.y * 128;
  __shared__ __align__(16) ushort Xs[2][128][64];
  __shared__ __align__(16) ushort Ws[2][128][64];
  f32x4 acc[4][4];
#pragma unroll
  for (int i = 0; i < 4; ++i)
#pragma unroll
    for (int j = 0; j < 4; ++j) acc[i][j] = (f32x4){0.f, 0.f, 0.f, 0.f};

  uint4 xa[4], xb[4];
  float lsum[4];

#define WSTAGE(bf, k0)                                                              \
  do {                                                                              \
    _Pragma("unroll") for (int p = 0; p < 4; ++p) {                                 \
      const int id = t + p * 256;                                                   \
      const int row = id >> 3, lch = id & 7;                                        \
      const int gch = lch ^ (row & 7);                                              \
      async16(&Ws[bf][row][lch * 8], W + (size_t)(n0 + row) * D_ + (k0) + gch * 8); \
    }                                                                               \
  } while (0)

#define XLOAD(k0)                                                                   \
  do {                                                                              \
    _Pragma("unroll") for (int p = 0; p < 4; ++p) {                                 \
      const int id = t + p * 256;                                                   \
      const int row = id >> 3, lch = id & 7;                                        \
      const int gch = lch ^ (row & 7);                                              \
      const size_t j16 = (size_t)(m0 + row) * D_ + (k0) + gch * 8;                  \
      xa[p] = *(const uint4*)(P0 + j16);                                            \
      xb[p] = *(const uint4*)(P1 + j16);                                            \
      const int tok = m0 + row;                                                     \
      const int li = ((((tok >> 11) * H_) + ((k0) >> 6)) << 11) + (tok & 2047);     \
      lsum[p] = l0[li] + l1[li];                                                    \
    }                                                                               \
  } while (0)

#define XWRITE(bf)                                                                  \
  do {                                                                              \
    _Pragma("unroll") for (int p = 0; p < 4; ++p) {                                 \
      const int id = t + p * 256;                                                   \
      const int row = id >> 3, lch = id & 7;                                        \
      const float inv = 1.f / lsum[p];                                              \
      const uint32_t* u0 = (const uint32_t*)&xa[p];                                 \
      const uint32_t* u1 = (const uint32_t*)&xb[p];                                 \
      uint4 o;                                                                      \
      uint32_t* uo = (uint32_t*)&o;                                                 \
      _Pragma("unroll") for (int m = 0; m < 4; ++m) {                               \
        const float lo = __uint_as_float(u0[m] << 16) + __uint_as_float(u1[m] << 16); \
        const float hi = __uint_as_float(u0[m] & 0xFFFF0000u) +                     \
                         __uint_as_float(u1[m] & 0xFFFF0000u);                      \
        uo[m] = pk2(lo * inv, hi * inv);                                            \
      }                                                                             \
      *(uint4*)&Xs[bf][row][lch * 8] = o;                                           \
    }                                                                               \
  } while (0)

  WSTAGE(0, 0);
  XLOAD(0);
  XWRITE(0);        // compiler waits vmcnt for xa/xb use here
  __syncthreads();  // drains Ws DMA + makes Xs writes visible
  const int NK = D_ / 64;  // 8
  for (int kt = 0; kt < NK; ++kt) {
    const int bf = kt & 1;
    if (kt + 1 < NK) {
      WSTAGE(bf ^ 1, (kt + 1) * 64);
      XLOAD((kt + 1) * 64);  // issue early; consumed after compute (T14)
    }
#pragma unroll
    for (int s = 0; s < 2; ++s) {
      short8 af[4], bt[4];
#pragma unroll
      for (int i = 0; i < 4; ++i) {
        const int rA = wn * 64 + i * 16 + c;
        af[i] = *(const short8*)&Ws[bf][rA][(((s * 4 + quad) ^ (rA & 7)) & 7) * 8];
        const int rB = wm * 64 + i * 16 + c;
        bt[i] = *(const short8*)&Xs[bf][rB][(((s * 4 + quad) ^ (rB & 7)) & 7) * 8];
      }
#pragma unroll
      for (int i = 0; i < 4; ++i)
#pragma unroll
        for (int j = 0; j < 4; ++j) acc[i][j] = MFMA16(af[i], bt[j], acc[i][j]);
    }
    if (kt + 1 < NK) {
      XWRITE(bf ^ 1);  // loads landed during compute; write other buffer
      __syncthreads();
    }
  }
#undef WSTAGE
#undef XLOAD
#undef XWRITE
#pragma unroll
  for (int i = 0; i < 4; ++i)
#pragma unroll
    for (int j = 0; j < 4; ++j) {
      const size_t off =
          (size_t)(m0 + wm * 64 + j * 16 + c) * D_ + n0 + wn * 64 + i * 16 + quad * 4;
      float4 v;
      v.x = acc[i][j][0]; v.y = acc[i][j][1]; v.z = acc[i][j][2]; v.w = acc[i][j][3];
      *(float4*)(out + off) = v;
    }
}

// ---------------- flash attention: r10-verified 8-wave / 128-q blocks (UNCHANGED) ----------------
__global__ __launch_bounds__(512) void attn_mfma(const ushort* __restrict__ Qb,
                                                 const ushort* __restrict__ Kb,
                                                 const uint32_t* __restrict__ pk,
                                                 ushort* __restrict__ P0,
                                                 ushort* __restrict__ P1,
                                                 float* __restrict__ l0,
                                                 float* __restrict__ l1) {
  const int qt128 = blockIdx.x >> 1, hf = blockIdx.x & 1;
  const int h = blockIdx.y, b = blockIdx.z;
  const int q0 = qt128 * 128;
  const int t = threadIdx.x;
  const int w = t >> 6, lane = t & 63, quad = lane >> 4, c = lane & 15;

  __shared__ __align__(16) ushort Ks[64][64];        // 8K: K rows, swizzled chunks
  __shared__ __align__(16) uint32_t KtU[64][32];     // 8K: V^T key-pair u32, swizzled
  __shared__ __align__(16) ushort QP[8][16][72];     // 18.4K: Qs[128][64] then Pq
  ushort(*Qs)[64] = (ushort(*)[64]) & QP[0][0][0];
  ushort(*Pq)[16][72] = QP;

  // ---- stage Q once (async DMA): 128 rows x 64 = 1024 chunks / 512 threads ----
#pragma unroll
  for (int p = 0; p < 2; ++p) {
    const int id = t + p * 512;
    const int row = id >> 3, lch = id & 7, gch = lch ^ (row & 7);
    async16(&Qs[row][lch * 8], Qb + (size_t)(b * N_ + q0 + row) * D_ + h * 64 + gch * 8);
  }
  __syncthreads();
  const int rq = (w << 4) + c;  // 0..127
  const short8 bq0 = *(const short8*)&Qs[rq][((quad ^ (rq & 7)) & 7) * 8];
  const short8 bq1 = *(const short8*)&Qs[rq][(((4 + quad) ^ (rq & 7)) & 7) * 8];

  short8 vones;
#pragma unroll
  for (int i = 0; i < 8; ++i) vones[i] = (short)0x3F80;  // bf16 1.0 splat

  f32x4 o[4];
#pragma unroll
  for (int i = 0; i < 4; ++i) o[i] = (f32x4){0.f, 0.f, 0.f, 0.f};
  f32x4 o5 = (f32x4){0.f, 0.f, 0.f, 0.f};  // l accumulator (ones-MFMA, rows identical)

  // staging roles (threads 0..255 only): key-pair, d-chunk — r8-verified path
  const int kp = t >> 3, ch = t & 7;
  const int r0 = 2 * kp, r1 = r0 + 1;
  const int ksw0 = ((ch ^ (r0 & 7)) & 7) * 8, ksw1 = ((ch ^ (r1 & 7)) & 7) * 8;
  const ushort* kb0 =
      Kb + (size_t)(b * N_ + hf * 1024 + 2 * kp) * D_ + h * 64 + ch * 8;
  const uint32_t* pkq =
      pk + ((size_t)(b * N_ + q0 + (w << 4) + c) << 6) + hf * 32;

  // prefetched tile data (registers; c0/c1 meaningful for t<256 only)
  uint4 c0, c1;
  if (t < 256) {
    c0 = *(const uint4*)kb0;
    c1 = *(const uint4*)(kb0 + D_);
  }
  uint2 cm = *(const uint2*)pkq;
  uint4 nx0, nx1; uint2 nxm;

  const int NT = 16;  // half the keys
  for (int kt = 0; kt < NT; ++kt) {
    __syncthreads();  // prior tile's frag reads (and initial Qs reads) done
    // ---- stage K tile from registers (rows + u32 key-pair transpose), t<256 ----
    if (t < 256) {
      *(uint4*)&Ks[r0][ksw0] = c0;
      *(uint4*)&Ks[r1][ksw1] = c1;
      const uint32_t* a0 = (const uint32_t*)&c0;
      const uint32_t* a1 = (const uint32_t*)&c1;
#pragma unroll
      for (int m = 0; m < 4; ++m) {
        const uint32_t lo = __builtin_amdgcn_perm(a1[m], a0[m], 0x05040100);  // even d
        const uint32_t hi = __builtin_amdgcn_perm(a1[m], a0[m], 0x07060302);  // odd d
        const int j0 = 2 * m, j1 = 2 * m + 1;
        KtU[ch * 8 + j0][(kp & 3) | ((((kp >> 2) ^ j0 ^ ch) & 7) << 2)] = lo;
        KtU[ch * 8 + j1][(kp & 3) | ((((kp >> 2) ^ j1 ^ ch) & 7) << 2)] = hi;
      }
    }
    __syncthreads();

    if (kt + 1 < NT) {  // prefetch next tile while computing
      if (t < 256) {
        const ushort* kbn = kb0 + (size_t)(kt + 1) * 64 * D_;
        nx0 = *(const uint4*)kbn;
        nx1 = *(const uint4*)(kbn + D_);
      }
      nxm = *(const uint2*)(pkq + (kt + 1) * 2);
    }

    // ---- S^T = K·Q^T; p = masked ? 0 : exp2(s) ----
#pragma unroll
    for (int tI = 0; tI < 4; ++tI) {
      const int rk = tI * 16 + c;
      const short8 aK0 = *(const short8*)&Ks[rk][((quad ^ (rk & 7)) & 7) * 8];
      const short8 aK1 = *(const short8*)&Ks[rk][(((4 + quad) ^ (rk & 7)) & 7) * 8];
      f32x4 z = (f32x4){0.f, 0.f, 0.f, 0.f};
      z = MFMA16(aK0, bq0, z);
      z = MFMA16(aK1, bq1, z);
      const uint32_t mw = (tI < 2) ? cm.x : cm.y;
      const int bb = ((tI & 1) << 4) + quad * 4;
      uint32_t pb[4];
#pragma unroll
      for (int r = 0; r < 4; ++r) {
        const float e = EXP2(z[r]);                       // unconditional
        pb[r] = ((mw >> (bb + r)) & 1u) ? 0u : __float_as_uint(e);
      }
      const uint32_t pw0 = __builtin_amdgcn_perm(pb[1], pb[0], 0x07060302);
      const uint32_t pw1 = __builtin_amdgcn_perm(pb[3], pb[2], 0x07060302);
      *(uint2*)&Pq[w][c][tI * 16 + quad * 4] = make_uint2(pw0, pw1);
    }

    // ---- O^T += V^T·P^T ; l via ones-MFMA ----
    const short8 bp0 = *(const short8*)&Pq[w][c][quad * 8];
    const short8 bp1 = *(const short8*)&Pq[w][c][32 + quad * 8];
    o5 = MFMA16(vones, bp0, o5);
    o5 = MFMA16(vones, bp1, o5);
#pragma unroll
    for (int dt = 0; dt < 4; ++dt) {
      const int dd = dt * 16 + c;
      const int g = (c & 7) ^ ((2 * dt + (c >> 3)) & 7);
      const short8 aV0 = *(const short8*)&KtU[dd][((quad ^ g) & 7) << 2];
      const short8 aV1 = *(const short8*)&KtU[dd][(((4 + quad) ^ g) & 7) << 2];
      o[dt] = MFMA16(aV0, bp0, o[dt]);
      o[dt] = MFMA16(aV1, bp1, o[dt]);
    }

    if (kt + 1 < NT) {
      if (t < 256) { c0 = nx0; c1 = nx1; }
      cm = nxm;
    }
  }

  // ---- epilogue: store PARTIAL O^T (bf16, unscaled) + partial l; no atomics ----
  ushort* Pp = hf ? P1 : P0;
  float* lp = hf ? l1 : l0;
#pragma unroll
  for (int dt = 0; dt < 4; ++dt) {
    uint2 uv;
    uv.x = pk2(o[dt][0], o[dt][1]);
    uv.y = pk2(o[dt][2], o[dt][3]);
    *(uint2*)(Pp + (size_t)(b * N_ + q0 + (w << 4) + c) * D_ + h * 64 + dt * 16 + quad * 4) = uv;
  }
  if (quad == 0) lp[((b * H_ + h) << 11) + q0 + (w << 4) + c] = o5[0];
}

extern "C" void kernel_launch(void* const* d_in, const int* in_sizes, int n_in,
                              void* d_out, int out_size, void* d_ws, size_t ws_size,
                              hipStream_t stream) {
  const float* queries = (const float*)d_in[0];
  const int* mask = (const int*)d_in[1];
  const float* Wq = (const float*)d_in[2];
  const float* Wk = (const float*)d_in[3];
  const float* Wc = (const float*)d_in[4];
  float* out = (float*)d_out;

  const size_t nTok = (size_t)B_ * N_;
  const size_t nXD = nTok * D_;
  const size_t nW = (size_t)D_ * D_;
  ushort* Xb = (ushort*)d_ws;
  ushort* Wqb = Xb + nXD;     // Wq|Wk|Wc contiguous
  ushort* Wkb = Wqb + nW;
  ushort* Wcb = Wkb + nW;
  ushort* Qb = Wcb + nW;
  ushort* Kb = Qb + nXD;
  ushort* Ab = Kb + nXD;
  uint32_t* pk = (uint32_t*)(Ab + nXD);
  // dead-region reuse during attn (all within verified footprint):
  ushort* P0 = Xb;            // bf16 partial O, half 0 (Xb dead after gemmQK)
  ushort* P1 = Ab;            // bf16 partial O, half 1
  float* l0 = (float*)Wqb;    // 256 KB in dead Wqb
  float* l1 = (float*)Wkb;    // 256 KB in dead Wkb

  prep<<<3168, 256, 0, stream>>>(queries, mask, Wq, Wk, Wc, Xb, Wqb, pk);
  gemmQK<<<dim3(D_ / 128, (int)(nTok / 128), 2), 256, 0, stream>>>(
      Xb, Wqb, Wkb, Qb, Kb, NORM2_, 1.0f);
  attn_mfma<<<dim3(32, H_, B_), 512, 0, stream>>>(Qb, Kb, pk, P0, P1, l0, l1);
  gemmOut<<<dim3(D_ / 128, (int)(nTok / 128)), 256, 0, stream>>>(
      P0, P1, l0, l1, Wcb, out);
}